// Round 1
// baseline (183.647 us; speedup 1.0000x reference)
//
#include <hip/hip_runtime.h>

// SymmetryControl: B=16, C=96, H=96, W=96 fp32.
// out[b,c,h,i] = num/den with
//   num = w0*x0 + sg0*w(i-24)*x(i-24) + sg1*w(i-48)*x(i-48) + sg2*w(i-72)*x(i-72)
//       + sg3*w(23-i)*x(23-i) + sg4*w(47-i)*x(47-i)     (all indices mod 96, same row)
//   den = w0 + sg0*w(i-24) + sg1*w(i-48) + sg2*w(i-72) + sg3*w(23-i) + sg4*w(47-i)
// sg = sigmoid(s[b, 0..4])
//
// Memory-bound: 170 MB compulsory traffic -> ~27 us floor at 6.3 TB/s.
// Rows are 384 B = 3 aligned 128 B cache lines; all 6 taps hit the same row,
// so L1 captures the reuse and HBM traffic stays compulsory.

#define WDIM 96
#define ROWS_PER_BLOCK 8

__global__ __launch_bounds__(WDIM * ROWS_PER_BLOCK)
void symctl_kernel(const float* __restrict__ x,
                   const float* __restrict__ s,
                   const float* __restrict__ w,
                   float* __restrict__ out,
                   int n_rows, int rows_per_batch) {
    const int i   = threadIdx.x;                                  // 0..95 angular index
    const int row = blockIdx.x * ROWS_PER_BLOCK + threadIdx.y;    // global row id
    if (row >= n_rows) return;

    const int b = row / rows_per_batch;   // batch index (div by constant 9216)
    const float* sb = s + b * 5;
    // sigmoid gates (broadcast loads, scalar-cached)
    const float sg0 = 1.0f / (1.0f + __expf(-sb[0]));
    const float sg1 = 1.0f / (1.0f + __expf(-sb[1]));
    const float sg2 = 1.0f / (1.0f + __expf(-sb[2]));
    const float sg3 = 1.0f / (1.0f + __expf(-sb[3]));
    const float sg4 = 1.0f / (1.0f + __expf(-sb[4]));

    // branchless mod-96 tap indices
    int i24 = i - 24; if (i24 < 0) i24 += WDIM;
    int i48 = i - 48; if (i48 < 0) i48 += WDIM;
    int i72 = i - 72; if (i72 < 0) i72 += WDIM;
    int f23 = 23 - i; if (f23 < 0) f23 += WDIM;
    int f47 = 47 - i; if (f47 < 0) f47 += WDIM;

    const long base = (long)row * WDIM;
    const float* __restrict__ xr = x + base;
    const float* __restrict__ wr = w + base;

    const float x0 = xr[i],   w0 = wr[i];
    const float xa = xr[i24], wa = wr[i24];
    const float xb = xr[i48], wb = wr[i48];
    const float xc = xr[i72], wc = wr[i72];
    const float xd = xr[f23], wd = wr[f23];
    const float xe = xr[f47], we = wr[f47];

    const float num = w0 * x0
                    + sg0 * (wa * xa)
                    + sg1 * (wb * xb)
                    + sg2 * (wc * xc)
                    + sg3 * (wd * xd)
                    + sg4 * (we * xe);
    const float den = w0
                    + sg0 * wa
                    + sg1 * wb
                    + sg2 * wc
                    + sg3 * wd
                    + sg4 * we;

    out[base + i] = num / den;
}

extern "C" void kernel_launch(void* const* d_in, const int* in_sizes, int n_in,
                              void* d_out, int out_size, void* d_ws, size_t ws_size,
                              hipStream_t stream) {
    const float* x = (const float*)d_in[0];
    const float* s = (const float*)d_in[1];
    const float* w = (const float*)d_in[2];
    float* out = (float*)d_out;

    const int n_rows = in_sizes[0] / WDIM;          // 16*96*96 = 147456
    const int rows_per_batch = 96 * 96;             // C*H = 9216
    const int grid = (n_rows + ROWS_PER_BLOCK - 1) / ROWS_PER_BLOCK;

    dim3 block(WDIM, ROWS_PER_BLOCK);
    symctl_kernel<<<grid, block, 0, stream>>>(x, s, w, out, n_rows, rows_per_batch);
}

// Round 2
// 157.939 us; speedup vs baseline: 1.1628x; 1.1628x over previous
//
#include <hip/hip_runtime.h>

// SymmetryControl: B=16, C=96, H=96, W=96 fp32.
// out[b,c,h,i] = num/den, 6 taps of the same 96-wide row (3 shifts + 2 flips),
// gated by sigmoid(s[b,0..4]).
//
// R2: float4 vectorization (all tap bases are multiples of 4; flip taps of one
// float4 segment never straddle the mod-96 wrap), per-block sigmoid via LDS,
// v_rcp_f32 for the divide. Attacks the 80% VALUBusy from R1.

#define WDIM 96
#define QDIM 24          // float4 segments per row
#define ROWS 32          // rows per block
#define RPB  9216        // rows per batch (C*H)

__global__ __launch_bounds__(QDIM * ROWS)
void symctl_kernel(const float* __restrict__ x,
                   const float* __restrict__ s,
                   const float* __restrict__ w,
                   float* __restrict__ out) {
    const int qx  = threadIdx.x;                       // 0..23 float4 segment
    const int row = blockIdx.x * ROWS + threadIdx.y;   // global row (uniform batch per block: RPB % ROWS == 0)
    const int b   = (blockIdx.x * ROWS) / RPB;         // scalar: batch index

    // per-block sigmoid gates
    __shared__ float sg[5];
    const int flat = threadIdx.y * QDIM + qx;
    if (flat < 5) sg[flat] = 1.0f / (1.0f + __expf(-s[b * 5 + flat]));
    __syncthreads();
    const float sg0 = sg[0], sg1 = sg[1], sg2 = sg[2], sg3 = sg[3], sg4 = sg[4];

    // tap bases in float4 units, mod 24
    int qa = qx - 6;  if (qa < 0) qa += QDIM;   // i-24
    int qb = qx - 12; if (qb < 0) qb += QDIM;   // i-48
    int qc = qx + 6;  if (qc >= QDIM) qc -= QDIM; // i-72  (== qx-18 mod 24)
    int qd = 5  - qx; if (qd < 0) qd += QDIM;   // flip base (20-4qx)/4
    int qe = 11 - qx; if (qe < 0) qe += QDIM;   // flip base (44-4qx)/4

    const float4* __restrict__ xr = (const float4*)(x + (size_t)row * WDIM);
    const float4* __restrict__ wr = (const float4*)(w + (size_t)row * WDIM);

    const float4 X0 = xr[qx], Xa = xr[qa], Xb = xr[qb], Xc = xr[qc], Xd = xr[qd], Xe = xr[qe];
    const float4 W0 = wr[qx], Wa = wr[qa], Wb = wr[qb], Wc = wr[qc], Wd = wr[qd], We = wr[qe];

    const float* x0p = (const float*)&X0; const float* w0p = (const float*)&W0;
    const float* xap = (const float*)&Xa; const float* wap = (const float*)&Wa;
    const float* xbp = (const float*)&Xb; const float* wbp = (const float*)&Wb;
    const float* xcp = (const float*)&Xc; const float* wcp = (const float*)&Wc;
    const float* xdp = (const float*)&Xd; const float* wdp = (const float*)&Wd;
    const float* xep = (const float*)&Xe; const float* wep = (const float*)&We;

    float4 res;
    float* rp = (float*)&res;
#pragma unroll
    for (int j = 0; j < 4; ++j) {
        const int r = 3 - j;  // flip taps are component-reversed
        const float w0 = w0p[j], wa = wap[j], wb = wbp[j], wc = wcp[j];
        const float wd = wdp[r], we = wep[r];
        const float ga = sg0 * wa, gb = sg1 * wb, gc = sg2 * wc;
        const float gd = sg3 * wd, ge = sg4 * we;

        float num = w0 * x0p[j];
        num = fmaf(ga, xap[j], num);
        num = fmaf(gb, xbp[j], num);
        num = fmaf(gc, xcp[j], num);
        num = fmaf(gd, xdp[r], num);
        num = fmaf(ge, xep[r], num);

        const float den = w0 + ga + gb + gc + gd + ge;
        rp[j] = num * __builtin_amdgcn_rcpf(den);
    }

    float4* outr = (float4*)(out + (size_t)row * WDIM);
    outr[qx] = res;
}

extern "C" void kernel_launch(void* const* d_in, const int* in_sizes, int n_in,
                              void* d_out, int out_size, void* d_ws, size_t ws_size,
                              hipStream_t stream) {
    const float* x = (const float*)d_in[0];
    const float* s = (const float*)d_in[1];
    const float* w = (const float*)d_in[2];
    float* out = (float*)d_out;

    const int n_rows = in_sizes[0] / WDIM;   // 147456
    const int grid = n_rows / ROWS;          // 4608

    dim3 block(QDIM, ROWS);
    symctl_kernel<<<grid, block, 0, stream>>>(x, s, w, out);
}

// Round 3
// 157.477 us; speedup vs baseline: 1.1662x; 1.0029x over previous
//
#include <hip/hip_runtime.h>

// SymmetryControl: B=16, C=96, H=96, W=96 fp32.
// out[b,c,h,i] = num/den, 6 taps of the same 96-wide row (3 shifts + 2 flips),
// gated by sigmoid(s[b,0..4]).
//
// R3: attack latency-boundedness (R2: VALU 16%, HBM 26%, VGPR=32 -> only ~4
// loads in flight). 192-thread blocks (3 waves, packs 10/CU),
// __launch_bounds__(192,6) -> ~84 VGPR cap so all 12 float4 loads stay
// outstanding in one batch. Sigmoids per-wave from scalar-loaded s (batch is
// block-uniform) -- no LDS, no barrier.

#define WDIM 96
#define QDIM 24          // float4 segments per row
#define ROWS 8           // rows per block (RPB % ROWS == 0)
#define RPB  9216        // rows per batch (C*H)

__global__ __launch_bounds__(QDIM * ROWS, 6)
void symctl_kernel(const float* __restrict__ x,
                   const float* __restrict__ s,
                   const float* __restrict__ w,
                   float* __restrict__ out) {
    const int qx      = threadIdx.x;                 // 0..23 float4 segment
    const int rowbase = blockIdx.x * ROWS;           // block-uniform
    const int row     = rowbase + threadIdx.y;
    const int b       = rowbase / RPB;               // scalar (uniform) batch index

    // sigmoid gates — s address is wave-uniform -> s_load; ~15 VALU per wave
    const float* sb = s + b * 5;
    const float sg0 = 1.0f / (1.0f + __expf(-sb[0]));
    const float sg1 = 1.0f / (1.0f + __expf(-sb[1]));
    const float sg2 = 1.0f / (1.0f + __expf(-sb[2]));
    const float sg3 = 1.0f / (1.0f + __expf(-sb[3]));
    const float sg4 = 1.0f / (1.0f + __expf(-sb[4]));

    // tap bases in float4 units, mod 24
    int qa = qx - 6;  if (qa < 0) qa += QDIM;        // i-24
    int qb = qx - 12; if (qb < 0) qb += QDIM;        // i-48
    int qc = qx + 6;  if (qc >= QDIM) qc -= QDIM;    // i-72
    int qd = 5  - qx; if (qd < 0) qd += QDIM;        // flip base (20-4qx)/4
    int qe = 11 - qx; if (qe < 0) qe += QDIM;        // flip base (44-4qx)/4

    const float4* __restrict__ xr = (const float4*)(x + (size_t)row * WDIM);
    const float4* __restrict__ wr = (const float4*)(w + (size_t)row * WDIM);

    // all 12 loads issued before any use -> 12 outstanding vmem ops
    const float4 X0 = xr[qx], Xa = xr[qa], Xb = xr[qb], Xc = xr[qc], Xd = xr[qd], Xe = xr[qe];
    const float4 W0 = wr[qx], Wa = wr[qa], Wb = wr[qb], Wc = wr[qc], Wd = wr[qd], We = wr[qe];

    const float* x0p = (const float*)&X0; const float* w0p = (const float*)&W0;
    const float* xap = (const float*)&Xa; const float* wap = (const float*)&Wa;
    const float* xbp = (const float*)&Xb; const float* wbp = (const float*)&Wb;
    const float* xcp = (const float*)&Xc; const float* wcp = (const float*)&Wc;
    const float* xdp = (const float*)&Xd; const float* wdp = (const float*)&Wd;
    const float* xep = (const float*)&Xe; const float* wep = (const float*)&We;

    float4 res;
    float* rp = (float*)&res;
#pragma unroll
    for (int j = 0; j < 4; ++j) {
        const int r = 3 - j;  // flip taps are component-reversed
        const float w0 = w0p[j];
        const float ga = sg0 * wap[j], gb = sg1 * wbp[j], gc = sg2 * wcp[j];
        const float gd = sg3 * wdp[r], ge = sg4 * wep[r];

        float num = w0 * x0p[j];
        num = fmaf(ga, xap[j], num);
        num = fmaf(gb, xbp[j], num);
        num = fmaf(gc, xcp[j], num);
        num = fmaf(gd, xdp[r], num);
        num = fmaf(ge, xep[r], num);

        const float den = w0 + ga + gb + gc + gd + ge;
        rp[j] = num * __builtin_amdgcn_rcpf(den);
    }

    float4* outr = (float4*)(out + (size_t)row * WDIM);
    outr[qx] = res;
}

extern "C" void kernel_launch(void* const* d_in, const int* in_sizes, int n_in,
                              void* d_out, int out_size, void* d_ws, size_t ws_size,
                              hipStream_t stream) {
    const float* x = (const float*)d_in[0];
    const float* s = (const float*)d_in[1];
    const float* w = (const float*)d_in[2];
    float* out = (float*)d_out;

    const int n_rows = in_sizes[0] / WDIM;   // 147456
    const int grid = n_rows / ROWS;          // 18432

    dim3 block(QDIM, ROWS);
    symctl_kernel<<<grid, block, 0, stream>>>(x, s, w, out);
}

// Round 4
// 148.989 us; speedup vs baseline: 1.2326x; 1.0570x over previous
//
#include <hip/hip_runtime.h>

// SymmetryControl: B=16, C=96, H=96, W=96 fp32.
// out[b,c,h,i] = num/den, 6 taps of the same 96-wide row, gated by sigmoid(s[b,:]).
//
// R4 theory: R1-R3 all hit a ~50 us wall re-reading taps through L1 (6x line-visit
// amplification; L1 delivers ~1 line / ~4.5 cyc / CU). Fix: move the 6x reuse into
// LDS. Quarter structure: for i = 24q + r, all 6 taps live at {(q',r),(q',23-r)},
// q' in 0..3:
//   shifts:  i-24 -> q-1,  i-48 -> q-2,  i-72 -> q-3   (same r)
//   flips:   23-i -> (-q)%4,  47-i -> (1-q)%4          (r' = 23-r)
// Phase 1: stream x,w as float4 (compulsory-only HBM traffic), write p = x*w and w
// to LDS. Phase 2: each thread reads 16 scalars (8 at r, 8 at 23-r), emits 4 outputs.

#define WDIM 96
#define ROWS 16          // rows per block (RPB % ROWS == 0)
#define RPB  9216        // rows per batch (C*H)
#define LSTR 100         // padded LDS row stride (floats): 16B-aligned rows, bank shift 4/row

__global__ __launch_bounds__(24 * ROWS)
void symctl_kernel(const float* __restrict__ x,
                   const float* __restrict__ s,
                   const float* __restrict__ w,
                   float* __restrict__ out) {
    __shared__ float pb[ROWS][LSTR];   // x*w products
    __shared__ float wb[ROWS][LSTR];   // weights

    const int t       = threadIdx.x;              // 0..23
    const int ry      = threadIdx.y;              // 0..ROWS-1
    const int rowbase = blockIdx.x * ROWS;        // block-uniform
    const int row     = rowbase + ry;
    const int b       = rowbase / RPB;            // uniform batch index

    // sigmoid gates (s address wave-uniform)
    const float* sb = s + b * 5;
    const float sg0 = 1.0f / (1.0f + __expf(-sb[0]));
    const float sg1 = 1.0f / (1.0f + __expf(-sb[1]));
    const float sg2 = 1.0f / (1.0f + __expf(-sb[2]));
    const float sg3 = 1.0f / (1.0f + __expf(-sb[3]));
    const float sg4 = 1.0f / (1.0f + __expf(-sb[4]));

    // ---- phase 1: pure float4 streaming into LDS ----
    const float4 x4 = ((const float4*)(x + (size_t)row * WDIM))[t];
    const float4 w4 = ((const float4*)(w + (size_t)row * WDIM))[t];
    float4 p4;
    p4.x = x4.x * w4.x; p4.y = x4.y * w4.y;
    p4.z = x4.z * w4.z; p4.w = x4.w * w4.w;
    *(float4*)&pb[ry][4 * t] = p4;
    *(float4*)&wb[ry][4 * t] = w4;

    __syncthreads();

    // ---- phase 2: quarter-structure gather, 4 outputs per thread ----
    const int r  = t;
    const int rm = 23 - t;
    const float* pr = &pb[ry][0];
    const float* wr = &wb[ry][0];

    float pq[4], aq[4], pP[4], aP[4];
#pragma unroll
    for (int q = 0; q < 4; ++q) {
        pq[q] = pr[24 * q + r];
        aq[q] = wr[24 * q + r];
        pP[q] = pr[24 * q + rm];
        aP[q] = wr[24 * q + rm];
    }

    float* orow = out + (size_t)row * WDIM + r;
#pragma unroll
    for (int q = 0; q < 4; ++q) {
        const int i1 = (q + 3) & 3;   // q-1
        const int i2 = (q + 2) & 3;   // q-2
        const int i3 = (q + 1) & 3;   // q-3
        const int i4 = (4 - q) & 3;   // -q
        const int i5 = (5 - q) & 3;   // 1-q

        float num = pq[q];
        num = fmaf(sg0, pq[i1], num);
        num = fmaf(sg1, pq[i2], num);
        num = fmaf(sg2, pq[i3], num);
        num = fmaf(sg3, pP[i4], num);
        num = fmaf(sg4, pP[i5], num);

        float den = aq[q];
        den = fmaf(sg0, aq[i1], den);
        den = fmaf(sg1, aq[i2], den);
        den = fmaf(sg2, aq[i3], den);
        den = fmaf(sg3, aP[i4], den);
        den = fmaf(sg4, aP[i5], den);

        orow[24 * q] = num * __builtin_amdgcn_rcpf(den);
    }
}

extern "C" void kernel_launch(void* const* d_in, const int* in_sizes, int n_in,
                              void* d_out, int out_size, void* d_ws, size_t ws_size,
                              hipStream_t stream) {
    const float* x = (const float*)d_in[0];
    const float* s = (const float*)d_in[1];
    const float* w = (const float*)d_in[2];
    float* out = (float*)d_out;

    const int n_rows = in_sizes[0] / WDIM;   // 147456
    const int grid = n_rows / ROWS;          // 9216

    dim3 block(24, ROWS);
    symctl_kernel<<<grid, block, 0, stream>>>(x, s, w, out);
}